// Round 1
// baseline (820.018 us; speedup 1.0000x reference)
//
#include <hip/hip_runtime.h>
#include <hip/hip_bf16.h>

// ---- sizes ----
#define HH 224
#define WWN 224
#define CCH 768
#define NBLK 8
#define BSZ 96
#define PI2_N 0.0280499344f   // 2*pi/224

typedef short v8s __attribute__((ext_vector_type(8)));
typedef float v4f __attribute__((ext_vector_type(4)));

__device__ inline float bf2f(short s) {
    unsigned int u = ((unsigned int)(unsigned short)s) << 16;
    return __builtin_bit_cast(float, u);
}
__device__ inline short f2bf(float f) {
    unsigned int u = __builtin_bit_cast(unsigned int, f);
    u = (u + 0x7FFFu + ((u >> 16) & 1u)) >> 16;   // RNE
    return (short)u;
}

// Stage 1: A1[blk][k][u] = sum_m W[blk][m][k] cos(2pi m u/224); A2 with sin.
__global__ __launch_bounds__(224) void k_build_U(const float* __restrict__ bw,
                                                 float* __restrict__ A1,
                                                 float* __restrict__ A2) {
    __shared__ float cosT[224], sinT[224], Wcol[96];
    int blk = blockIdx.x / 96, k = blockIdx.x % 96;
    int t = threadIdx.x;
    float ang = (float)t * PI2_N;
    cosT[t] = cosf(ang); sinT[t] = sinf(ang);
    if (t < 96) Wcol[t] = bw[(blk * 96 + t) * 96 + k];
    __syncthreads();
    float s1 = 0.f, s2 = 0.f;
    int u = t;
    for (int m = 0; m < 96; ++m) {
        int idx = (m * u) % 224;
        s1 += Wcol[m] * cosT[idx];
        s2 += Wcol[m] * sinT[idx];
    }
    A1[(blk * 96 + k) * 224 + u] = s1;
    A2[(blk * 96 + k) * 224 + u] = s2;
}

// Stage 2: T[blk][w][u] (bf16) and bias vector V[blk][w] (added at spatial h==0).
__global__ __launch_bounds__(224) void k_build_T(const float* __restrict__ A1,
                                                 const float* __restrict__ A2,
                                                 const float* __restrict__ gates,
                                                 const float* __restrict__ bias,
                                                 short* __restrict__ T,
                                                 float* __restrict__ V) {
    __shared__ float cosT[224], sinT[224], ck[96], sk[96];
    int blk = blockIdx.x / 224, w = blockIdx.x % 224;
    int t = threadIdx.x;
    float ang = (float)t * PI2_N;
    cosT[t] = cosf(ang); sinT[t] = sinf(ang);
    __syncthreads();
    if (t < 96) {
        float a = (t == 0) ? 1.f : 2.f;
        int idx = (t * w) % 224;
        ck[t] = a * cosT[idx];
        sk[t] = a * sinT[idx];
    }
    __syncthreads();
    float g = 1.f / (1.f + expf(-gates[blk]));
    int u = t;
    float s = 0.f;
    for (int k = 0; k < 96; ++k)
        s += ck[k] * A1[(blk * 96 + k) * 224 + u] + sk[k] * A2[(blk * 96 + k) * 224 + u];
    int dw = (w - u + 224) % 224;
    float p = 0.f;
    for (int k = 96; k < 113; ++k) {
        float a = (k == 112) ? 1.f : 2.f;
        p += a * cosT[(k * dw) % 224];
    }
    T[blk * 50176 + w * 224 + u] = f2bf((g * s + p) * (1.f / 224.f));
    if (t == 0) {   // bias lands only on spatial row h=0 (sqrt(H)*delta from ifft of const)
        float vs = 0.f;
        for (int k = 0; k < 96; ++k) vs += bias[blk * 96 + k] * (ck[k] - sk[k]);
        V[blk * 224 + w] = g * vs;
    }
}

__global__ void k_cvt_pw(const float* __restrict__ pw, short* __restrict__ pwb, int n) {
    int i = blockIdx.x * 256 + threadIdx.x;
    if (i < n) pwb[i] = f2bf(pw[i]);
}

// Spectral apply: per (b,h,blk): out(224w x 96c) = T_blk @ X(224u x 96c). bf16 MFMA.
__global__ __launch_bounds__(256, 2) void k_spectral(const float* __restrict__ x,
                                                     const short* __restrict__ T,
                                                     const float* __restrict__ V,
                                                     short* __restrict__ XB) {
    __shared__ short XT[96 * 232];   // XT[c][u], pitch 232 (16B-aligned rows)
    int id = blockIdx.x;
    int blk = id & 7;
    int h = (id >> 3) % 224;
    int b = id / (8 * 224);
    const float* xp = x + (size_t)(b * 224 + h) * 224 * 768 + blk * 96;
    int tid = threadIdx.x;
    for (int idx = tid; idx < 224 * 24; idx += 256) {
        int u = idx / 24, c4 = (idx % 24) * 4;
        float4 vv = *(const float4*)(xp + u * 768 + c4);
        XT[(c4 + 0) * 232 + u] = f2bf(vv.x);
        XT[(c4 + 1) * 232 + u] = f2bf(vv.y);
        XT[(c4 + 2) * 232 + u] = f2bf(vv.z);
        XT[(c4 + 3) * 232 + u] = f2bf(vv.w);
    }
    __syncthreads();
    int lane = tid & 63, wave = tid >> 6;
    int q = lane >> 4, ln = lane & 15;
    v4f acc[4][6];
    #pragma unroll
    for (int i = 0; i < 4; ++i)
        #pragma unroll
        for (int ct = 0; ct < 6; ++ct) acc[i][ct] = {0.f, 0.f, 0.f, 0.f};
    const short* Tb = T + blk * 50176;
    #pragma unroll
    for (int ks = 0; ks < 7; ++ks) {
        int k0 = ks * 32 + q * 8;
        v8s a[4];
        #pragma unroll
        for (int i = 0; i < 4; ++i) {
            int wt = wave + 4 * i;
            int row = (wt < 14 ? wt : 13) * 16 + ln;   // clamp: waves 2,3 duplicate tile 13; stores guarded
            a[i] = *(const v8s*)(Tb + row * 224 + k0); // A[m=ln][k=q*8+j], 16B from L2
        }
        #pragma unroll
        for (int ct = 0; ct < 6; ++ct) {
            v8s bfr = *(const v8s*)(&XT[(ct * 16 + ln) * 232 + k0]); // B[k][n=ln]
            #pragma unroll
            for (int i = 0; i < 4; ++i)
                acc[i][ct] = __builtin_amdgcn_mfma_f32_16x16x32_bf16(a[i], bfr, acc[i][ct], 0, 0, 0);
        }
    }
    short* XBp = XB + (size_t)(b * 224 + h) * 224 * 768 + blk * 96;
    #pragma unroll
    for (int i = 0; i < 4; ++i) {
        int wt = wave + 4 * i;
        if (wt < 14) {
            #pragma unroll
            for (int reg = 0; reg < 4; ++reg) {
                int ww = wt * 16 + q * 4 + reg;   // C/D: col=lane&15, row=quad*4+reg
                float vadd = (h == 0) ? V[blk * 224 + ww] : 0.f;
                #pragma unroll
                for (int ct = 0; ct < 6; ++ct)
                    XBp[(size_t)ww * 768 + ct * 16 + ln] = f2bf(acc[i][ct][reg] + vadd);
            }
        }
    }
}

// Projection GEMM: out = x_out + rescale*(x_out @ proj_w^T + proj_b). 128x128 tile, BK=64.
__global__ __launch_bounds__(256, 2) void k_gemm(const short* __restrict__ XB,
                                                 const short* __restrict__ PWB,
                                                 const float* __restrict__ pb,
                                                 const float* __restrict__ rescale,
                                                 float* __restrict__ out) {
    __shared__ short As[128 * 72], Bs[128 * 72];   // pad 64->72 (bank-conflict-free-ish)
    int id = blockIdx.x;
    int mblk = id / 6, nblk = id % 6;   // m-major: consecutive ids share A rows in L2/L3
    int m0 = mblk * 128, n0 = nblk * 128;
    int tid = threadIdx.x;
    int lane = tid & 63, wave = tid >> 6;
    int q = lane >> 4, ln = lane & 15;
    int wm = (wave & 1) * 64, wn = (wave >> 1) * 64;
    v4f acc[4][4];
    #pragma unroll
    for (int mt = 0; mt < 4; ++mt)
        #pragma unroll
        for (int nt = 0; nt < 4; ++nt) acc[mt][nt] = {0.f, 0.f, 0.f, 0.f};
    for (int kb = 0; kb < 12; ++kb) {
        int k0 = kb * 64;
        #pragma unroll
        for (int j = 0; j < 4; ++j) {
            int cid = j * 256 + tid;
            int row = cid >> 3, kc = (cid & 7) * 8;
            *(v8s*)(As + row * 72 + kc) = *(const v8s*)(XB + (size_t)(m0 + row) * 768 + k0 + kc);
            *(v8s*)(Bs + row * 72 + kc) = *(const v8s*)(PWB + (size_t)(n0 + row) * 768 + k0 + kc);
        }
        __syncthreads();
        #pragma unroll
        for (int k2 = 0; k2 < 2; ++k2) {
            int kk = k2 * 32 + q * 8;
            v8s a[4], bfr[4];
            #pragma unroll
            for (int mt = 0; mt < 4; ++mt) a[mt] = *(const v8s*)(As + (wm + mt * 16 + ln) * 72 + kk);
            #pragma unroll
            for (int nt = 0; nt < 4; ++nt) bfr[nt] = *(const v8s*)(Bs + (wn + nt * 16 + ln) * 72 + kk);
            #pragma unroll
            for (int mt = 0; mt < 4; ++mt)
                #pragma unroll
                for (int nt = 0; nt < 4; ++nt)
                    acc[mt][nt] = __builtin_amdgcn_mfma_f32_16x16x32_bf16(a[mt], bfr[nt], acc[mt][nt], 0, 0, 0);
        }
        __syncthreads();
    }
    float rs = rescale[0];
    float pbv[4];
    #pragma unroll
    for (int nt = 0; nt < 4; ++nt) pbv[nt] = pb[n0 + wn + nt * 16 + ln];
    #pragma unroll
    for (int mt = 0; mt < 4; ++mt)
        #pragma unroll
        for (int reg = 0; reg < 4; ++reg) {
            int r = m0 + wm + mt * 16 + q * 4 + reg;
            #pragma unroll
            for (int nt = 0; nt < 4; ++nt) {
                int c = n0 + wn + nt * 16 + ln;
                float resid = bf2f(XB[(size_t)r * 768 + c]);
                out[(size_t)r * 768 + c] = resid + rs * (acc[mt][nt][reg] + pbv[nt]);
            }
        }
}

extern "C" void kernel_launch(void* const* d_in, const int* in_sizes, int n_in,
                              void* d_out, int out_size, void* d_ws, size_t ws_size,
                              hipStream_t stream) {
    const float* x      = (const float*)d_in[0];
    const float* bw     = (const float*)d_in[1];
    const float* bias   = (const float*)d_in[2];
    const float* gates  = (const float*)d_in[3];
    const float* pw     = (const float*)d_in[4];
    const float* pb     = (const float*)d_in[5];
    const float* rescale= (const float*)d_in[6];
    float* out = (float*)d_out;
    char* ws = (char*)d_ws;
    // ws layout
    short* T   = (short*)(ws + 0);            // 8*224*224*2      =   802816
    short* PWB = (short*)(ws + 802816);       // 768*768*2        =  1179648
    float* V   = (float*)(ws + 1982464);      // 8*224*4          =     7168
    float* A1  = (float*)(ws + 1989632);      // 8*96*224*4       =   688128
    float* A2  = (float*)(ws + 2677760);      // 8*96*224*4       =   688128
    short* XB  = (short*)(ws + 3366912);      // 2*224*224*768*2  = 154140672  (~157.5MB total)

    k_build_U<<<dim3(768), dim3(224), 0, stream>>>(bw, A1, A2);
    k_build_T<<<dim3(1792), dim3(224), 0, stream>>>(A1, A2, gates, bias, T, V);
    k_cvt_pw<<<dim3(2304), dim3(256), 0, stream>>>(pw, PWB, 768 * 768);
    k_spectral<<<dim3(2 * 224 * 8), dim3(256), 0, stream>>>(x, T, V, XB);
    k_gemm<<<dim3(784 * 6), dim3(256), 0, stream>>>(XB, PWB, pb, rescale, out);
}

// Round 2
// 752.845 us; speedup vs baseline: 1.0892x; 1.0892x over previous
//
#include <hip/hip_runtime.h>
#include <hip/hip_bf16.h>

#define PI2_N 0.0280499344f   // 2*pi/224

typedef short v8s __attribute__((ext_vector_type(8)));
typedef float v4f __attribute__((ext_vector_type(4)));

__device__ inline float bf2f(short s) {
    unsigned int u = ((unsigned int)(unsigned short)s) << 16;
    return __builtin_bit_cast(float, u);
}
__device__ inline short f2bf(float f) {
    unsigned int u = __builtin_bit_cast(unsigned int, f);
    u = (u + 0x7FFFu + ((u >> 16) & 1u)) >> 16;   // RNE
    return (short)u;
}
__device__ inline void gl_lds16(const short* g, short* l) {
    __builtin_amdgcn_global_load_lds(
        (const __attribute__((address_space(1))) void*)g,
        (__attribute__((address_space(3))) void*)l, 16, 0, 0);
}

// Stage 1: A1[blk][k][u] = sum_m W[blk][m][k] cos(2pi m u/224); A2 with sin.
__global__ __launch_bounds__(224) void k_build_U(const float* __restrict__ bw,
                                                 float* __restrict__ A1,
                                                 float* __restrict__ A2) {
    __shared__ float cosT[224], sinT[224], Wcol[96];
    int blk = blockIdx.x / 96, k = blockIdx.x % 96;
    int t = threadIdx.x;
    float ang = (float)t * PI2_N;
    cosT[t] = cosf(ang); sinT[t] = sinf(ang);
    if (t < 96) Wcol[t] = bw[(blk * 96 + t) * 96 + k];
    __syncthreads();
    float s1 = 0.f, s2 = 0.f;
    int u = t;
    for (int m = 0; m < 96; ++m) {
        int idx = (m * u) % 224;
        s1 += Wcol[m] * cosT[idx];
        s2 += Wcol[m] * sinT[idx];
    }
    A1[(blk * 96 + k) * 224 + u] = s1;
    A2[(blk * 96 + k) * 224 + u] = s2;
}

// Stage 2: T[blk][w][u] (bf16) and bias vector V[blk][w] (added at spatial h==0).
__global__ __launch_bounds__(224) void k_build_T(const float* __restrict__ A1,
                                                 const float* __restrict__ A2,
                                                 const float* __restrict__ gates,
                                                 const float* __restrict__ bias,
                                                 short* __restrict__ T,
                                                 float* __restrict__ V) {
    __shared__ float cosT[224], sinT[224], ck[96], sk[96];
    int blk = blockIdx.x / 224, w = blockIdx.x % 224;
    int t = threadIdx.x;
    float ang = (float)t * PI2_N;
    cosT[t] = cosf(ang); sinT[t] = sinf(ang);
    __syncthreads();
    if (t < 96) {
        float a = (t == 0) ? 1.f : 2.f;
        int idx = (t * w) % 224;
        ck[t] = a * cosT[idx];
        sk[t] = a * sinT[idx];
    }
    __syncthreads();
    float g = 1.f / (1.f + expf(-gates[blk]));
    int u = t;
    float s = 0.f;
    for (int k = 0; k < 96; ++k)
        s += ck[k] * A1[(blk * 96 + k) * 224 + u] + sk[k] * A2[(blk * 96 + k) * 224 + u];
    int dw = (w - u + 224) % 224;
    float p = 0.f;
    for (int k = 96; k < 113; ++k) {
        float a = (k == 112) ? 1.f : 2.f;
        p += a * cosT[(k * dw) % 224];
    }
    T[blk * 50176 + w * 224 + u] = f2bf((g * s + p) * (1.f / 224.f));
    if (t == 0) {   // bias lands only on spatial row h=0
        float vs = 0.f;
        for (int k = 0; k < 96; ++k) vs += bias[blk * 96 + k] * (ck[k] - sk[k]);
        V[blk * 224 + w] = g * vs;
    }
}

__global__ void k_cvt_pw(const float* __restrict__ pw, short* __restrict__ pwb, int n) {
    int i = blockIdx.x * 256 + threadIdx.x;
    if (i < n) pwb[i] = f2bf(pw[i]);
}

// Spectral apply: per (b,h,blk): out(224w x 96c) = T_blk @ X(224u x 96c). bf16 MFMA.
__global__ __launch_bounds__(256, 2) void k_spectral(const float* __restrict__ x,
                                                     const short* __restrict__ T,
                                                     const float* __restrict__ V,
                                                     short* __restrict__ XB) {
    __shared__ short XT[96 * 232];   // XT[c][u], pitch 232
    int id = blockIdx.x;
    int blk = id & 7;
    int h = (id >> 3) % 224;
    int b = id / (8 * 224);
    const float* xp = x + (size_t)(b * 224 + h) * 224 * 768 + blk * 96;
    int tid = threadIdx.x;
    // stage X^T into LDS as bf16, packed u-pair b32 writes
    for (int idx = tid; idx < 112 * 24; idx += 256) {
        int u2 = idx / 24, c4 = (idx % 24) * 4;
        int u = u2 * 2;
        float4 v0 = *(const float4*)(xp + u * 768 + c4);
        float4 v1 = *(const float4*)(xp + (u + 1) * 768 + c4);
        unsigned p0 = (unsigned short)f2bf(v0.x) | ((unsigned)(unsigned short)f2bf(v1.x) << 16);
        unsigned p1 = (unsigned short)f2bf(v0.y) | ((unsigned)(unsigned short)f2bf(v1.y) << 16);
        unsigned p2 = (unsigned short)f2bf(v0.z) | ((unsigned)(unsigned short)f2bf(v1.z) << 16);
        unsigned p3 = (unsigned short)f2bf(v0.w) | ((unsigned)(unsigned short)f2bf(v1.w) << 16);
        *(unsigned*)(&XT[(c4 + 0) * 232 + u]) = p0;
        *(unsigned*)(&XT[(c4 + 1) * 232 + u]) = p1;
        *(unsigned*)(&XT[(c4 + 2) * 232 + u]) = p2;
        *(unsigned*)(&XT[(c4 + 3) * 232 + u]) = p3;
    }
    __syncthreads();
    int lane = tid & 63, wave = tid >> 6;
    int q = lane >> 4, ln = lane & 15;
    v4f acc[4][6];
    #pragma unroll
    for (int i = 0; i < 4; ++i)
        #pragma unroll
        for (int ct = 0; ct < 6; ++ct) acc[i][ct] = {0.f, 0.f, 0.f, 0.f};
    const short* Tb = T + blk * 50176;
    #pragma unroll
    for (int ks = 0; ks < 7; ++ks) {
        int k0 = ks * 32 + q * 8;
        v8s a[4];
        #pragma unroll
        for (int i = 0; i < 4; ++i) {
            int wt = wave + 4 * i;
            int row = (wt < 14 ? wt : 13) * 16 + ln;   // clamp; stores guarded
            a[i] = *(const v8s*)(Tb + row * 224 + k0);
        }
        #pragma unroll
        for (int ct = 0; ct < 6; ++ct) {
            v8s bfr = *(const v8s*)(&XT[(ct * 16 + ln) * 232 + k0]);
            #pragma unroll
            for (int i = 0; i < 4; ++i)
                acc[i][ct] = __builtin_amdgcn_mfma_f32_16x16x32_bf16(a[i], bfr, acc[i][ct], 0, 0, 0);
        }
    }
    short* XBp = XB + (size_t)(b * 224 + h) * 224 * 768 + blk * 96;
    #pragma unroll
    for (int i = 0; i < 4; ++i) {
        int wt = wave + 4 * i;
        if (wt < 14) {
            #pragma unroll
            for (int reg = 0; reg < 4; ++reg) {
                int ww = wt * 16 + q * 4 + reg;   // C/D: col=lane&15, row=quad*4+reg
                float vadd = (h == 0) ? V[blk * 224 + ww] : 0.f;
                #pragma unroll
                for (int ct = 0; ct < 6; ++ct)
                    XBp[(size_t)ww * 768 + ct * 16 + ln] = f2bf(acc[i][ct][reg] + vadd);
            }
        }
    }
}

// Projection GEMM: out = x_out + rescale*(x_out @ proj_w^T + proj_b).
// 128x128 tile, BK=64, global_load_lds(16B) + XOR-swizzled unpadded LDS,
// XCD-aware block mapping (6 same-A-tile blocks -> same XCD's L2).
__global__ __launch_bounds__(256, 2) void k_gemm(const short* __restrict__ XB,
                                                 const short* __restrict__ PWB,
                                                 const float* __restrict__ pb,
                                                 const float* __restrict__ rescale,
                                                 float* __restrict__ out) {
    __shared__ short As[128 * 64], Bs[128 * 64];   // unpadded; XOR swizzle on 16B granules
    int id = blockIdx.x;
    int xcd = id & 7, slot = id >> 3;              // block->XCD is round-robin id%8
    int mblk = xcd * 98 + slot / 6;                // 784 mblks = 8 xcds * 98
    int nblk = slot % 6;
    int m0 = mblk * 128, n0 = nblk * 128;
    int tid = threadIdx.x;
    int lane = tid & 63, wave = tid >> 6;
    int q = lane >> 4, ln = lane & 15;
    int wm = (wave & 1) * 64, wn = (wave >> 1) * 64;
    v4f acc[4][4];
    #pragma unroll
    for (int mt = 0; mt < 4; ++mt)
        #pragma unroll
        for (int nt = 0; nt < 4; ++nt) acc[mt][nt] = {0.f, 0.f, 0.f, 0.f};
    for (int kb = 0; kb < 12; ++kb) {
        int k0 = kb * 64;
        // async stage: each wave stages 32 rows of As and Bs (4 issues x 8 rows x 128B)
        #pragma unroll
        for (int j = 0; j < 4; ++j) {
            int r0 = wave * 32 + j * 8;
            int row = r0 + (lane >> 3);
            int col8 = (lane & 7) ^ (row & 7);     // swizzled source for LDS slot (row, lane&7)
            gl_lds16(XB + (size_t)(m0 + row) * 768 + k0 + col8 * 8, As + r0 * 64);
            gl_lds16(PWB + (size_t)(n0 + row) * 768 + k0 + col8 * 8, Bs + r0 * 64);
        }
        __syncthreads();
        #pragma unroll
        for (int k2 = 0; k2 < 2; ++k2) {
            int kk = k2 * 32 + q * 8;
            v8s a[4], bfr[4];
            #pragma unroll
            for (int mt = 0; mt < 4; ++mt) {
                int r = wm + mt * 16 + ln;
                a[mt] = *(const v8s*)(As + r * 64 + (kk ^ ((r & 7) * 8)));
            }
            #pragma unroll
            for (int nt = 0; nt < 4; ++nt) {
                int r = wn + nt * 16 + ln;
                bfr[nt] = *(const v8s*)(Bs + r * 64 + (kk ^ ((r & 7) * 8)));
            }
            #pragma unroll
            for (int mt = 0; mt < 4; ++mt)
                #pragma unroll
                for (int nt = 0; nt < 4; ++nt)
                    acc[mt][nt] = __builtin_amdgcn_mfma_f32_16x16x32_bf16(a[mt], bfr[nt], acc[mt][nt], 0, 0, 0);
        }
        __syncthreads();
    }
    float rs = rescale[0];
    float pbv[4];
    #pragma unroll
    for (int nt = 0; nt < 4; ++nt) pbv[nt] = pb[n0 + wn + nt * 16 + ln];
    #pragma unroll
    for (int mt = 0; mt < 4; ++mt)
        #pragma unroll
        for (int reg = 0; reg < 4; ++reg) {
            int r = m0 + wm + mt * 16 + q * 4 + reg;
            #pragma unroll
            for (int nt = 0; nt < 4; ++nt) {
                int c = n0 + wn + nt * 16 + ln;
                float resid = bf2f(XB[(size_t)r * 768 + c]);   // L2-hit: same XCD fetched this A tile
                out[(size_t)r * 768 + c] = resid + rs * (acc[mt][nt][reg] + pbv[nt]);
            }
        }
}

extern "C" void kernel_launch(void* const* d_in, const int* in_sizes, int n_in,
                              void* d_out, int out_size, void* d_ws, size_t ws_size,
                              hipStream_t stream) {
    const float* x      = (const float*)d_in[0];
    const float* bw     = (const float*)d_in[1];
    const float* bias   = (const float*)d_in[2];
    const float* gates  = (const float*)d_in[3];
    const float* pw     = (const float*)d_in[4];
    const float* pb     = (const float*)d_in[5];
    const float* rescale= (const float*)d_in[6];
    float* out = (float*)d_out;
    char* ws = (char*)d_ws;
    short* T   = (short*)(ws + 0);            // 802816 B
    short* PWB = (short*)(ws + 802816);       // 1179648 B
    float* V   = (float*)(ws + 1982464);      // 7168 B
    float* A1  = (float*)(ws + 1989632);      // 688128 B
    float* A2  = (float*)(ws + 2677760);      // 688128 B
    short* XB  = (short*)(ws + 3366912);      // 154140672 B

    k_build_U<<<dim3(768), dim3(224), 0, stream>>>(bw, A1, A2);
    k_build_T<<<dim3(1792), dim3(224), 0, stream>>>(A1, A2, gates, bias, T, V);
    k_cvt_pw<<<dim3(2304), dim3(256), 0, stream>>>(pw, PWB, 768 * 768);
    k_spectral<<<dim3(2 * 224 * 8), dim3(256), 0, stream>>>(x, T, V, XB);
    k_gemm<<<dim3(784 * 6), dim3(256), 0, stream>>>(XB, PWB, pb, rescale, out);
}